// Round 3
// baseline (675.359 us; speedup 1.0000x reference)
//
#include <hip/hip_runtime.h>
#include <hip/hip_bf16.h>
#include <cstdint>

typedef __bf16 bf16_t;
typedef __attribute__((ext_vector_type(8))) __bf16 bf16x8;
typedef __attribute__((ext_vector_type(4))) __bf16 bf16x4;
typedef __attribute__((ext_vector_type(4))) float f32x4;

#define B_ 8
#define T_ 2048
#define D_ 2048
#define M_ (B_ * T_)   // 16384
#define N2_ (2 * D_)   // 4096 (interleaved z/h columns)
#define K_ D_          // 2048

#define BM 128
#define BN 128
#define BK 32
#define NC 32
#define CHUNK (T_ / NC)  // 64

// ---------------- conversion kernels ----------------

__global__ void conv_x_kernel(const float4* __restrict__ in, bf16x4* __restrict__ out, int n4) {
    int i = blockIdx.x * blockDim.x + threadIdx.x;
    if (i >= n4) return;
    float4 v = in[i];
    bf16x4 o = { (bf16_t)v.x, (bf16_t)v.y, (bf16_t)v.z, (bf16_t)v.w };
    out[i] = o;
}

// Pack Wz/Wh interleaved by row: Wb[2e] = Wz[e], Wb[2e+1] = Wh[e]
__global__ void conv_w_kernel(const float4* __restrict__ Wz, const float4* __restrict__ Wh,
                              bf16x4* __restrict__ Wb, int n4, int d4) {
    int i = blockIdx.x * blockDim.x + threadIdx.x;
    if (i >= n4) return;
    int row = i / d4;
    int c = i - row * d4;
    float4 vz = Wz[i];
    float4 vh = Wh[i];
    bf16x4 oz = { (bf16_t)vz.x, (bf16_t)vz.y, (bf16_t)vz.z, (bf16_t)vz.w };
    bf16x4 oh = { (bf16_t)vh.x, (bf16_t)vh.y, (bf16_t)vh.z, (bf16_t)vh.w };
    Wb[(size_t)(2 * row) * d4 + c] = oz;
    Wb[(size_t)(2 * row + 1) * d4 + c] = oh;
}

// ---------------- GEMM + epilogue ----------------

__device__ __forceinline__ void gload_lds16(const void* g, void* l) {
    __builtin_amdgcn_global_load_lds(
        (__attribute__((address_space(1))) void*)(g),
        (__attribute__((address_space(3))) void*)(l), 16, 0, 0);
}

__global__ __launch_bounds__(256, 2) void gemm_fused(
    const bf16_t* __restrict__ Xb,   // [M_][K_]
    const bf16_t* __restrict__ Wb,   // [N2_][K_] row n: even=Wz[n/2], odd=Wh[n/2]
    const float* __restrict__ bz, const float* __restrict__ bh,
    bf16_t* __restrict__ Aco,        // [M_][D_]  a = 1 - z
    bf16_t* __restrict__ Bco)        // [M_][D_]  b = z * h_tilde
{
    __shared__ bf16_t sA[BM * BK];   // 8 KB, [128][32]
    __shared__ bf16_t sB[BN * BK];   // 8 KB

    const int t = threadIdx.x;
    const int wave = t >> 6, lane = t & 63;
    const int wr = wave >> 1, wc = wave & 1;
    const int bm0 = blockIdx.y * BM;
    const int bn0 = blockIdx.x * BN;

    // staging: round j (0/1): thread t covers tile row j*64 + (t>>2), k-col (t&3)*8
    const int srow = t >> 2;
    const int scol = (t & 3) * 8;
    const bf16_t* gA = Xb + (size_t)(bm0 + srow) * K_ + scol;
    const bf16_t* gB = Wb + (size_t)(bn0 + srow) * K_ + scol;

    const int fr = lane & 15;        // A row / B col within 16x16 fragment
    const int kg = (lane >> 4) * 8;  // k offset within BK

    f32x4 acc[4][4] = {};

    for (int k0 = 0; k0 < K_; k0 += BK) {
#pragma unroll
        for (int j = 0; j < 2; ++j) {
            gload_lds16(gA + (size_t)(j * 64) * K_ + k0,
                        (char*)sA + j * 4096 + wave * 1024);
            gload_lds16(gB + (size_t)(j * 64) * K_ + k0,
                        (char*)sB + j * 4096 + wave * 1024);
        }
        __syncthreads();

        bf16x8 av[4], bv[4];
#pragma unroll
        for (int mi = 0; mi < 4; ++mi)
            av[mi] = *(const bf16x8*)&sA[(wr * 64 + mi * 16 + fr) * BK + kg];
#pragma unroll
        for (int ni = 0; ni < 4; ++ni)
            bv[ni] = *(const bf16x8*)&sB[(wc * 64 + ni * 16 + fr) * BK + kg];

#pragma unroll
        for (int mi = 0; mi < 4; ++mi)
#pragma unroll
            for (int ni = 0; ni < 4; ++ni)
                acc[mi][ni] = __builtin_amdgcn_mfma_f32_16x16x32_bf16(
                    av[mi], bv[ni], acc[mi][ni], 0, 0, 0);
        __syncthreads();
    }

    // Epilogue: pair even(z)/odd(h) columns via shfl_xor(1), write a and b coeffs.
    const int rquad = (lane >> 4) * 4;
#pragma unroll
    for (int mi = 0; mi < 4; ++mi) {
#pragma unroll
        for (int ni = 0; ni < 4; ++ni) {
#pragma unroll
            for (int r = 0; r < 4; ++r) {
                float v = acc[mi][ni][r];
                float other = __shfl_xor(v, 1);
                int m = bm0 + wr * 64 + mi * 16 + rquad + r;
                int n2 = bn0 + wc * 64 + ni * 16 + fr;
                int ch = n2 >> 1;
                float zraw = (lane & 1) ? other : v;
                float z = 1.0f / (1.0f + __expf(-(zraw + bz[ch])));
                if (lane & 1) {
                    float hv = v + bh[ch];
                    Bco[(size_t)m * D_ + ch] = (bf16_t)(z * hv);
                } else {
                    Aco[(size_t)m * D_ + ch] = (bf16_t)(1.0f - z);
                }
            }
        }
    }
}

// ---------------- scan kernels ----------------

// Pass 1: per-chunk affine composition (A, B): h_out = A*h_in + B
__global__ void scan_chunk_summary(const bf16_t* __restrict__ Aco, const bf16_t* __restrict__ Bco,
                                   float* __restrict__ cA, float* __restrict__ cB) {
    int d = blockIdx.x * blockDim.x + threadIdx.x;
    int c = blockIdx.y, bb = blockIdx.z;
    size_t base = ((size_t)bb * T_ + (size_t)c * CHUNK) * D_ + d;
    float A = 1.0f, Bv = 0.0f;
#pragma unroll 4
    for (int tt = 0; tt < CHUNK; ++tt) {
        float a = (float)Aco[base + (size_t)tt * D_];
        float b = (float)Bco[base + (size_t)tt * D_];
        A *= a;
        Bv = a * Bv + b;
    }
    size_t ci = ((size_t)bb * NC + c) * D_ + d;
    cA[ci] = A;
    cB[ci] = Bv;
}

// Pass 2: sequential carry across chunks (tiny)
__global__ void scan_carry(const float* __restrict__ cA, const float* __restrict__ cB,
                           const float* __restrict__ h_prev, float* __restrict__ carry) {
    int idx = blockIdx.x * blockDim.x + threadIdx.x;  // over B_*D_
    int bb = idx / D_, d = idx - bb * D_;
    float h = h_prev[idx];
    for (int c = 0; c < NC; ++c) {
        size_t ci = ((size_t)bb * NC + c) * D_ + d;
        carry[ci] = h;
        h = cA[ci] * h + cB[ci];
    }
}

// Pass 3: apply recurrence within chunk, write outputs (+ final state)
__global__ void scan_apply(const bf16_t* __restrict__ Aco, const bf16_t* __restrict__ Bco,
                           const float* __restrict__ carry, float* __restrict__ out,
                           float* __restrict__ last) {
    int d = blockIdx.x * blockDim.x + threadIdx.x;
    int c = blockIdx.y, bb = blockIdx.z;
    size_t ci = ((size_t)bb * NC + c) * D_ + d;
    float h = carry[ci];
    size_t base = ((size_t)bb * T_ + (size_t)c * CHUNK) * D_ + d;
    for (int tt = 0; tt < CHUNK; ++tt) {
        float a = (float)Aco[base + (size_t)tt * D_];
        float b = (float)Bco[base + (size_t)tt * D_];
        h = a * h + b;
        out[base + (size_t)tt * D_] = h;
    }
    if (c == NC - 1) last[(size_t)bb * D_ + d] = h;
}

// ---------------- launch ----------------

extern "C" void kernel_launch(void* const* d_in, const int* in_sizes, int n_in,
                              void* d_out, int out_size, void* d_ws, size_t ws_size,
                              hipStream_t stream) {
    const float* x      = (const float*)d_in[0];
    const float* h_prev = (const float*)d_in[1];
    const float* Wz     = (const float*)d_in[2];
    const float* bz     = (const float*)d_in[3];
    const float* Wh     = (const float*)d_in[4];
    const float* bh     = (const float*)d_in[5];

    float* out  = (float*)d_out;
    float* last = out + (size_t)M_ * D_;

    char* ws = (char*)d_ws;
    bf16_t* Xb  = (bf16_t*)ws;                                   // M_*K_ bf16 (64 MB)
    bf16_t* Wb  = (bf16_t*)(ws + (size_t)M_ * K_ * 2);           // N2_*K_ bf16 (16 MB)
    bf16_t* Aco = (bf16_t*)((char*)Wb + (size_t)N2_ * K_ * 2);   // M_*D_ bf16 (64 MB)
    bf16_t* Bco = Aco + (size_t)M_ * D_;                         // M_*D_ bf16 (64 MB)
    float*  cA  = (float*)((char*)Bco + (size_t)M_ * D_ * 2);    // B_*NC*D_ f32 (2 MB)
    float*  cB  = cA + (size_t)B_ * NC * D_;                     // 2 MB
    float*  carry = cB + (size_t)B_ * NC * D_;                   // 2 MB

    {
        int n4 = M_ * K_ / 4;
        conv_x_kernel<<<(n4 + 255) / 256, 256, 0, stream>>>((const float4*)x, (bf16x4*)Xb, n4);
    }
    {
        int n4 = D_ * D_ / 4;
        conv_w_kernel<<<(n4 + 255) / 256, 256, 0, stream>>>((const float4*)Wz, (const float4*)Wh,
                                                            (bf16x4*)Wb, n4, D_ / 4);
    }
    gemm_fused<<<dim3(N2_ / BN, M_ / BM), 256, 0, stream>>>(Xb, Wb, bz, bh, Aco, Bco);
    scan_chunk_summary<<<dim3(D_ / 256, NC, B_), 256, 0, stream>>>(Aco, Bco, cA, cB);
    scan_carry<<<(B_ * D_) / 256, 256, 0, stream>>>(cA, cB, h_prev, carry);
    scan_apply<<<dim3(D_ / 256, NC, B_), 256, 0, stream>>>(Aco, Bco, carry, out, last);
}

// Round 7
// 596.556 us; speedup vs baseline: 1.1321x; 1.1321x over previous
//
#include <hip/hip_runtime.h>
#include <hip/hip_bf16.h>
#include <cstdint>

typedef __bf16 bf16_t;
typedef __attribute__((ext_vector_type(8))) __bf16 bf16x8;
typedef __attribute__((ext_vector_type(4))) __bf16 bf16x4;
typedef __attribute__((ext_vector_type(4))) float f32x4;

#define B_ 8
#define T_ 2048
#define D_ 2048
#define M_ (B_ * T_)   // 16384
#define N2_ (2 * D_)   // 4096 (interleaved z/h columns)
#define K_ D_          // 2048
#define NT (K_ / 64)   // 32 K-tiles of BK=64

#define NC 32
#define CHUNK (T_ / NC)  // 64

#define BAR() __builtin_amdgcn_s_barrier()
#define WAIT_LGKM0() asm volatile("s_waitcnt lgkmcnt(0)" ::: "memory")
#define WAIT_VM(n) asm volatile("s_waitcnt vmcnt(" #n ")" ::: "memory")

// ---------------- conversion kernels ----------------

__global__ void conv_x_kernel(const float4* __restrict__ in, bf16x4* __restrict__ out, int n4) {
    int i = blockIdx.x * blockDim.x + threadIdx.x;
    if (i >= n4) return;
    float4 v = in[i];
    bf16x4 o = { (bf16_t)v.x, (bf16_t)v.y, (bf16_t)v.z, (bf16_t)v.w };
    out[i] = o;
}

// Pack Wz/Wh interleaved by row: Wb[2e] = Wz[e], Wb[2e+1] = Wh[e]
__global__ void conv_w_kernel(const float4* __restrict__ Wz, const float4* __restrict__ Wh,
                              bf16x4* __restrict__ Wb, int n4, int d4) {
    int i = blockIdx.x * blockDim.x + threadIdx.x;
    if (i >= n4) return;
    int row = i / d4;
    int c = i - row * d4;
    float4 vz = Wz[i];
    float4 vh = Wh[i];
    bf16x4 oz = { (bf16_t)vz.x, (bf16_t)vz.y, (bf16_t)vz.z, (bf16_t)vz.w };
    bf16x4 oh = { (bf16_t)vh.x, (bf16_t)vh.y, (bf16_t)vh.z, (bf16_t)vh.w };
    Wb[(size_t)(2 * row) * d4 + c] = oz;
    Wb[(size_t)(2 * row + 1) * d4 + c] = oh;
}

// ---------------- GEMM (256x256, BK=64, 8-phase, swizzled LDS) ----------------

__device__ __forceinline__ void gload_lds16(const bf16_t* g, char* l) {
    __builtin_amdgcn_global_load_lds(
        (__attribute__((address_space(1))) void*)(g),
        (__attribute__((address_space(3))) void*)(l), 16, 0, 0);
}

// LDS map (per buffer p in {0,1}):  A at p*65536, B at p*65536+32768.
// Logical tile [256 rows][64 k] bf16, row stride 128B; within a row, 16B chunk
// c stored at chunk slot c ^ (row & 7)  (T2 XOR swizzle, bank-conflict-free).
// global_load_lds writes linearly; the global SOURCE address is pre-inverse-swizzled.

__global__ __launch_bounds__(512, 2) void gemm_fused(
    const bf16_t* __restrict__ Xb,   // [M_][K_]
    const bf16_t* __restrict__ Wb,   // [N2_][K_] (row 2e = Wz[e], 2e+1 = Wh[e])
    const float* __restrict__ bz, const float* __restrict__ bh,
    bf16_t* __restrict__ Aco,        // [M_][D_]  a = 1 - z
    bf16_t* __restrict__ Bco)        // [M_][D_]  b = z * h_tilde
{
    __shared__ __attribute__((aligned(16))) char lds[131072];

    const int t = threadIdx.x;
    const int wave = t >> 6, lane = t & 63;
    const int wr = wave >> 2, wc = wave & 3;       // 2 x 4 wave grid
    const int fr = lane & 15, ln4 = lane >> 4;
    const int fr7 = fr & 7;
    const int bn0 = blockIdx.x * 256;
    const int bm0 = blockIdx.y * 256;

    // ---- staging geometry (per-thread) ----
    const int l3 = lane >> 3, l7 = lane & 7;
    const int schunk = (l7 ^ l3) * 8;   // inverse-swizzled source chunk, in elements
    const int srow = wave * 8 + l3;     // row within a 64-row j-block

    // ---- read geometry ----
    const int csA[2] = { ((0 + ln4) ^ fr7) * 16, ((4 + ln4) ^ fr7) * 16 }; // kh=0,1
    const int rbaseA = wr * 16384 + fr * 128;  // + mi*2048 + csA[kh]
    const int rbaseB = wc * 8192 + fr * 128;   // + ni*2048 + csA[kh]

    auto stageA = [&](int buf, int h, int u) {
        const bf16_t* g = Xb + (size_t)(bm0 + h * 128 + srow) * K_ + u * 64 + schunk;
        char* l0 = lds + buf * 65536 + h * 16384 + wave * 1024;
        gload_lds16(g, l0);
        gload_lds16(g + (size_t)64 * K_, l0 + 8192);
    };
    auto stageB = [&](int buf, int h, int u) {
        const bf16_t* g = Wb + (size_t)(bn0 + h * 128 + srow) * K_ + u * 64 + schunk;
        char* l0 = lds + buf * 65536 + 32768 + h * 16384 + wave * 1024;
        gload_lds16(g, l0);
        gload_lds16(g + (size_t)64 * K_, l0 + 8192);
    };

#define RD_A(p, mi, kh) (*(const bf16x8*)(lds + (p) * 65536 + rbaseA + (mi) * 2048 + csA[kh]))
#define RD_B(p, ni, kh) (*(const bf16x8*)(lds + (p) * 65536 + 32768 + rbaseB + (ni) * 2048 + csA[kh]))

    f32x4 acc[8][4] = {};
    bf16x8 afr[4][2], bfr[4][2];

    // ---- prologue: tile0 complete + tile1 A-halves; 4 halves (8 loads) in flight ----
    stageA(0, 0, 0); stageA(0, 1, 0); stageB(0, 0, 0); stageB(0, 1, 0);
    stageA(1, 0, 1); stageA(1, 1, 1);
    WAIT_VM(4);   // tile0 landed; tile1 A-halves (4 loads) outstanding
    BAR();

    for (int u = 0; u < NT; ++u) {
        const int p = u & 1;

        // ---- SP1: 12 ds_reads; stage (u+1).B0 -> buf p^1; MFMA Q(m0,n01) ----
#pragma unroll
        for (int mi = 0; mi < 4; ++mi)
#pragma unroll
            for (int kh = 0; kh < 2; ++kh)
                afr[mi][kh] = RD_A(p, mi, kh);
#pragma unroll
        for (int ni = 0; ni < 2; ++ni)
#pragma unroll
            for (int kh = 0; kh < 2; ++kh)
                bfr[ni][kh] = RD_B(p, ni, kh);
        if (u + 1 < NT) stageB(p ^ 1, 0, u + 1);
        BAR();
        __builtin_amdgcn_s_setprio(1);
#pragma unroll
        for (int mi = 0; mi < 4; ++mi)
#pragma unroll
            for (int ni = 0; ni < 2; ++ni)
#pragma unroll
                for (int kh = 0; kh < 2; ++kh)
                    acc[mi][ni] = __builtin_amdgcn_mfma_f32_16x16x32_bf16(
                        afr[mi][kh], bfr[ni][kh], acc[mi][ni], 0, 0, 0);
        __builtin_amdgcn_s_setprio(0);
        BAR();

        // ---- SP2: 4 ds_reads; stage (u+1).B1; MFMA Q(m0,n23) ----
#pragma unroll
        for (int ni = 2; ni < 4; ++ni)
#pragma unroll
            for (int kh = 0; kh < 2; ++kh)
                bfr[ni][kh] = RD_B(p, ni, kh);
        if (u + 1 < NT) stageB(p ^ 1, 1, u + 1);
        BAR();
        __builtin_amdgcn_s_setprio(1);
#pragma unroll
        for (int mi = 0; mi < 4; ++mi)
#pragma unroll
            for (int ni = 2; ni < 4; ++ni)
#pragma unroll
                for (int kh = 0; kh < 2; ++kh)
                    acc[mi][ni] = __builtin_amdgcn_mfma_f32_16x16x32_bf16(
                        afr[mi][kh], bfr[ni][kh], acc[mi][ni], 0, 0, 0);
        __builtin_amdgcn_s_setprio(0);
        BAR();

        // ---- SP3: 8 ds_reads (A mi 4-7); lgkmcnt(0)+BAR certifies buf p fully
        //      read by ALL waves; then stage (u+2).A0 -> buf p; MFMA Q(m1,n01) ----
#pragma unroll
        for (int mi = 0; mi < 4; ++mi)
#pragma unroll
            for (int kh = 0; kh < 2; ++kh)
                afr[mi][kh] = RD_A(p, mi + 4, kh);
        WAIT_LGKM0();
        BAR();
        if (u + 2 < NT) stageA(p, 0, u + 2);
        __builtin_amdgcn_s_setprio(1);
#pragma unroll
        for (int mi = 0; mi < 4; ++mi)
#pragma unroll
            for (int ni = 0; ni < 2; ++ni)
#pragma unroll
                for (int kh = 0; kh < 2; ++kh)
                    acc[mi + 4][ni] = __builtin_amdgcn_mfma_f32_16x16x32_bf16(
                        afr[mi][kh], bfr[ni][kh], acc[mi + 4][ni], 0, 0, 0);
        __builtin_amdgcn_s_setprio(0);
        BAR();

        // ---- SP4: stage (u+2).A1; MFMA Q(m1,n23); counted vmcnt; barrier ----
        if (u + 2 < NT) stageA(p, 1, u + 2);
        __builtin_amdgcn_s_setprio(1);
#pragma unroll
        for (int mi = 0; mi < 4; ++mi)
#pragma unroll
            for (int ni = 2; ni < 4; ++ni)
#pragma unroll
                for (int kh = 0; kh < 2; ++kh)
                    acc[mi + 4][ni] = __builtin_amdgcn_mfma_f32_16x16x32_bf16(
                        afr[mi][kh], bfr[ni][kh], acc[mi + 4][ni], 0, 0, 0);
        __builtin_amdgcn_s_setprio(0);
        if (u < NT - 2)       { WAIT_VM(4); }   // tile u+1 landed; u+2 A-halves in flight
        else if (u == NT - 2) { WAIT_VM(0); }   // drain for the final tile
        BAR();
    }

    // ---- epilogue: a = 1-z, b = z*h_tilde ----
    float bzv[4], bhv[4];
#pragma unroll
    for (int ni = 0; ni < 4; ++ni) {
        int ch = (bn0 + wc * 64 + ni * 16 + fr) >> 1;
        bzv[ni] = bz[ch];
        bhv[ni] = bh[ch];
    }
#pragma unroll
    for (int mi = 0; mi < 8; ++mi) {
#pragma unroll
        for (int ni = 0; ni < 4; ++ni) {
#pragma unroll
            for (int q = 0; q < 4; ++q) {
                float v = acc[mi][ni][q];
                float other = __shfl_xor(v, 1);
                int m = bm0 + wr * 128 + mi * 16 + ln4 * 4 + q;
                int n2 = bn0 + wc * 64 + ni * 16 + fr;
                int ch = n2 >> 1;
                float zraw = (lane & 1) ? other : v;
                float z = 1.0f / (1.0f + __expf(-(zraw + bzv[ni])));
                if (lane & 1) {
                    Bco[(size_t)m * D_ + ch] = (bf16_t)(z * (v + bhv[ni]));
                } else {
                    Aco[(size_t)m * D_ + ch] = (bf16_t)(1.0f - z);
                }
            }
        }
    }
}

// ---------------- scan kernels ----------------

__global__ void scan_chunk_summary(const bf16_t* __restrict__ Aco, const bf16_t* __restrict__ Bco,
                                   float* __restrict__ cA, float* __restrict__ cB) {
    int d = blockIdx.x * blockDim.x + threadIdx.x;
    int c = blockIdx.y, bb = blockIdx.z;
    size_t base = ((size_t)bb * T_ + (size_t)c * CHUNK) * D_ + d;
    float A = 1.0f, Bv = 0.0f;
#pragma unroll 4
    for (int tt = 0; tt < CHUNK; ++tt) {
        float a = (float)Aco[base + (size_t)tt * D_];
        float b = (float)Bco[base + (size_t)tt * D_];
        A *= a;
        Bv = a * Bv + b;
    }
    size_t ci = ((size_t)bb * NC + c) * D_ + d;
    cA[ci] = A;
    cB[ci] = Bv;
}

__global__ void scan_carry(const float* __restrict__ cA, const float* __restrict__ cB,
                           const float* __restrict__ h_prev, float* __restrict__ carry) {
    int idx = blockIdx.x * blockDim.x + threadIdx.x;  // over B_*D_
    int bb = idx / D_, d = idx - bb * D_;
    float h = h_prev[idx];
    for (int c = 0; c < NC; ++c) {
        size_t ci = ((size_t)bb * NC + c) * D_ + d;
        carry[ci] = h;
        h = cA[ci] * h + cB[ci];
    }
}

__global__ void scan_apply(const bf16_t* __restrict__ Aco, const bf16_t* __restrict__ Bco,
                           const float* __restrict__ carry, float* __restrict__ out,
                           float* __restrict__ last) {
    int d = blockIdx.x * blockDim.x + threadIdx.x;
    int c = blockIdx.y, bb = blockIdx.z;
    size_t ci = ((size_t)bb * NC + c) * D_ + d;
    float h = carry[ci];
    size_t base = ((size_t)bb * T_ + (size_t)c * CHUNK) * D_ + d;
    for (int tt = 0; tt < CHUNK; ++tt) {
        float a = (float)Aco[base + (size_t)tt * D_];
        float b = (float)Bco[base + (size_t)tt * D_];
        h = a * h + b;
        out[base + (size_t)tt * D_] = h;
    }
    if (c == NC - 1) last[(size_t)bb * D_ + d] = h;
}

// ---------------- launch ----------------

extern "C" void kernel_launch(void* const* d_in, const int* in_sizes, int n_in,
                              void* d_out, int out_size, void* d_ws, size_t ws_size,
                              hipStream_t stream) {
    const float* x      = (const float*)d_in[0];
    const float* h_prev = (const float*)d_in[1];
    const float* Wz     = (const float*)d_in[2];
    const float* bz     = (const float*)d_in[3];
    const float* Wh     = (const float*)d_in[4];
    const float* bh     = (const float*)d_in[5];

    float* out  = (float*)d_out;
    float* last = out + (size_t)M_ * D_;

    char* ws = (char*)d_ws;
    bf16_t* Xb  = (bf16_t*)ws;                                   // M_*K_ bf16 (64 MB)
    bf16_t* Wb  = (bf16_t*)(ws + (size_t)M_ * K_ * 2);           // N2_*K_ bf16 (16 MB)
    bf16_t* Aco = (bf16_t*)((char*)Wb + (size_t)N2_ * K_ * 2);   // M_*D_ bf16 (64 MB)
    bf16_t* Bco = Aco + (size_t)M_ * D_;                         // M_*D_ bf16 (64 MB)
    float*  cA  = (float*)((char*)Bco + (size_t)M_ * D_ * 2);    // 2 MB
    float*  cB  = cA + (size_t)B_ * NC * D_;                     // 2 MB
    float*  carry = cB + (size_t)B_ * NC * D_;                   // 2 MB

    {
        int n4 = M_ * K_ / 4;
        conv_x_kernel<<<(n4 + 255) / 256, 256, 0, stream>>>((const float4*)x, (bf16x4*)Xb, n4);
    }
    {
        int n4 = D_ * D_ / 4;
        conv_w_kernel<<<(n4 + 255) / 256, 256, 0, stream>>>((const float4*)Wz, (const float4*)Wh,
                                                            (bf16x4*)Wb, n4, D_ / 4);
    }
    gemm_fused<<<dim3(N2_ / 256, M_ / 256), 512, 0, stream>>>(Xb, Wb, bz, bh, Aco, Bco);
    scan_chunk_summary<<<dim3(D_ / 256, NC, B_), 256, 0, stream>>>(Aco, Bco, cA, cB);
    scan_carry<<<(B_ * D_) / 256, 256, 0, stream>>>(cA, cB, h_prev, carry);
    scan_apply<<<dim3(D_ / 256, NC, B_), 256, 0, stream>>>(Aco, Bco, carry, out, last);
}